// Round 9
// baseline (339.239 us; speedup 1.0000x reference)
//
#include <hip/hip_runtime.h>
#include <float.h>
#include <stdint.h>

// MimiEuclideanCodebook: argmin_k ||x_n - e_k||^2 then gather e_k.
// R9: barrier-free K-loop. A-tile (128 rows, fp16 head|residual) LDS-resident
// (132 KB, converted in prologue, ONE barrier). B streams straight from L2
// into VGPRs (per-lane 16B loads from row-major ec) with an explicit 2-deep
// register pipeline -> no per-stage __syncthreads, no vmcnt(0) drain (the R8
// wall: 1 wave/SIMD + 384 barriers = 4x the MFMA floor).
// Split-precision virtual K=768: xh*eh + xl*eh + xh*el (bitwise-identical
// distances to R8). Top-2 across k-tiles in regs; exact-fp32 repair.

#define EPSILON 1e-5f
#define DELTA   1e-3f

constexpr int D     = 256;
constexpr int K_TOT = 2048;

// A LDS layout (halves): chunk c (0..63) x row r (0..127) at c*APH + r*8.
// APH=1032 (129 slots) staggers the 4 quads by 4 banks -> conflict-free b128.
constexpr int APH     = 1032;
constexpr int DYN_LDS = 64 * APH * 2;   // 132096 bytes (A only)

typedef _Float16 half8v __attribute__((ext_vector_type(8)));
typedef _Float16 half4v __attribute__((ext_vector_type(4)));
typedef float    f32x4  __attribute__((ext_vector_type(4)));

// ---------------- prep: ec (half+residual) + esq + counter ----------------
__global__ void prep_kernel(const float* __restrict__ es,
                            const float* __restrict__ usage,
                            _Float16* __restrict__ ec,
                            float* __restrict__ esq,
                            int* __restrict__ counter) {
  const int bx   = blockIdx.x;
  const int t    = threadIdx.x;
  const int wid  = t >> 6;
  const int lane = t & 63;
  if (bx < K_TOT / 4) {
    const int k = bx * 4 + wid;
    const float u = fmaxf(usage[k], EPSILON);
    const float4 v = *(const float4*)(es + (size_t)k * D + lane * 4);
    float4 e;
    e.x = v.x / u; e.y = v.y / u; e.z = v.z / u; e.w = v.w / u;  // exact div
    half4v h, lo;
    h.x = (_Float16)e.x; lo.x = (_Float16)(e.x - (float)h.x);
    h.y = (_Float16)e.y; lo.y = (_Float16)(e.y - (float)h.y);
    h.z = (_Float16)e.z; lo.z = (_Float16)(e.z - (float)h.z);
    h.w = (_Float16)e.w; lo.w = (_Float16)(e.w - (float)h.w);
    *(half4v*)(ec + (size_t)k * 512 + lane * 4)       = h;
    *(half4v*)(ec + (size_t)k * 512 + 256 + lane * 4) = lo;
    float s = e.x * e.x + e.y * e.y + e.z * e.z + e.w * e.w;
    #pragma unroll
    for (int m = 1; m < 64; m <<= 1) s += __shfl_xor(s, m, 64);
    if (lane == 0) esq[k] = s;
  } else {
    if (t == 0) *counter = 0;
  }
}

// ---------------- A-resident, barrier-free MFMA GEMM + running top-2 ----------------
__global__ __launch_bounds__(256, 1)
void mm_kernel(const float* __restrict__ x, const _Float16* __restrict__ ec,
               const float* __restrict__ esq, float4* __restrict__ p4, int N) {
  extern __shared__ __align__(16) _Float16 lds[];
  const int t    = threadIdx.x;
  const int lane = t & 63;
  const int q    = lane >> 4;
  const int wid  = t >> 6;
  const int wn   = wid >> 1;
  const int wk   = wid & 1;
  const int n0   = blockIdx.x * 128;

  // ---- prologue: convert x tile into LDS-resident A (head | residual) ----
  #pragma unroll 4
  for (int i = 0; i < 32; ++i) {
    const int idx = i * 256 + t;
    const int r   = idx >> 6;
    const int c   = idx & 63;
    const float* src = x + (size_t)(n0 + r) * D + (c & 31) * 8;
    const float4 f0 = *(const float4*)src;
    const float4 f1 = *(const float4*)(src + 4);
    const float f[8] = {f0.x, f0.y, f0.z, f0.w, f1.x, f1.y, f1.z, f1.w};
    half8v hv;
    if (c < 32) {
      #pragma unroll
      for (int e = 0; e < 8; ++e) hv[e] = (_Float16)f[e];
    } else {
      #pragma unroll
      for (int e = 0; e < 8; ++e) {
        const _Float16 h = (_Float16)f[e];
        hv[e] = (_Float16)(f[e] - (float)h);
      }
    }
    *(half8v*)&lds[c * APH + r * 8] = hv;
  }
  __syncthreads();   // the ONLY barrier

  // loop-invariant offsets / pointers
  int arow[4];
  #pragma unroll
  for (int mi = 0; mi < 4; ++mi) arow[mi] = (wn * 64 + mi * 16 + (lane & 15)) * 8;
  const _Float16* pBg[4];
  #pragma unroll
  for (int ni = 0; ni < 4; ++ni)
    pBg[ni] = ec + (size_t)(wk * 64 + ni * 16 + (lane & 15)) * 512 + q * 8;

  float rd0[4][4], rd1[4][4];
  int   ri0[4][4];
  #pragma unroll
  for (int mi = 0; mi < 4; ++mi)
    #pragma unroll
    for (int r = 0; r < 4; ++r) {
      rd0[mi][r] = FLT_MAX; rd1[mi][r] = FLT_MAX; ri0[mi][r] = 0x7fffffff;
    }

  // register pipeline: bf 2-deep, af 1-deep
  half8v af0[4], bf0[4], bf1[4];
  #pragma unroll
  for (int ni = 0; ni < 4; ++ni) {
    bf0[ni] = *(const half8v*)(pBg[ni]);        // (kt0,vs0) boff=0
    bf1[ni] = *(const half8v*)(pBg[ni] + 32);   // (kt0,vs1) boff=32
  }
  #pragma unroll
  for (int mi = 0; mi < 4; ++mi)
    af0[mi] = *(const half8v*)&lds[q * APH + arow[mi]];   // as=0

  for (int kt = 0; kt < 16; ++kt) {
    const int kb  = kt * (128 * 512);
    const int kbn = kb + 128 * 512;   // prefetch past end lands in ws (safe)
    int   kc[4];
    float eqv[4];
    #pragma unroll
    for (int ni = 0; ni < 4; ++ni) {
      kc[ni]  = kt * 128 + wk * 64 + ni * 16 + (lane & 15);
      eqv[ni] = esq[kc[ni]];
    }

    f32x4 acc[4][4] = {};

    // 24 BK=32 stages. A k-step: as = vs<16 ? vs : vs-16 (chunks 4as+q).
    // B halves offset: boff(vs) = (vs<8 ? vs : vs-8)*32  (vs>=16 -> residual).
    #pragma unroll
    for (int vs = 0; vs < 24; ++vs) {
      half8v bfn[4], afn[4];
      {  // prefetch B for stage vs+2 (crosses into next kt at vs=22,23)
        const int nvs  = (vs < 22) ? vs + 2 : vs - 22;
        const int base = (vs < 22) ? kb : kbn;
        const int boff = (nvs < 8 ? nvs : nvs - 8) * 32;
        #pragma unroll
        for (int ni = 0; ni < 4; ++ni)
          bfn[ni] = *(const half8v*)(pBg[ni] + base + boff);
      }
      {  // prefetch A for stage vs+1
        const int nvs = (vs < 23) ? vs + 1 : 0;
        const int as  = (nvs < 16) ? nvs : nvs - 16;
        #pragma unroll
        for (int mi = 0; mi < 4; ++mi)
          afn[mi] = *(const half8v*)&lds[(as * 4 + q) * APH + arow[mi]];
      }
      #pragma unroll
      for (int mi = 0; mi < 4; ++mi)
        #pragma unroll
        for (int ni = 0; ni < 4; ++ni)
          acc[mi][ni] = __builtin_amdgcn_mfma_f32_16x16x32_f16(
              af0[mi], bf0[ni], acc[mi][ni], 0, 0, 0);
      #pragma unroll
      for (int z = 0; z < 4; ++z) { af0[z] = afn[z]; bf0[z] = bf1[z]; bf1[z] = bfn[z]; }
    }

    // merge this k-tile into running top-2 (ascending k, strict '<')
    #pragma unroll
    for (int ni = 0; ni < 4; ++ni) {
      #pragma unroll
      for (int mi = 0; mi < 4; ++mi) {
        #pragma unroll
        for (int r = 0; r < 4; ++r) {
          const float d = fmaf(-2.f, acc[mi][ni][r], eqv[ni]);
          if (d < rd0[mi][r]) {
            rd1[mi][r] = rd0[mi][r]; rd0[mi][r] = d; ri0[mi][r] = kc[ni];
          } else {
            rd1[mi][r] = fminf(rd1[mi][r], d);
          }
        }
      }
    }
  }

  // cross-lane reduce over 16 k-cols; one p4 write per (row, wk)
  #pragma unroll
  for (int mi = 0; mi < 4; ++mi) {
    #pragma unroll
    for (int r = 0; r < 4; ++r) {
      float d0 = rd0[mi][r], d1 = rd1[mi][r];
      int   i0 = ri0[mi][r];
      #pragma unroll
      for (int off = 1; off < 16; off <<= 1) {
        const float od0 = __shfl_xor(d0, off, 16);
        const int   oi0 = __shfl_xor(i0, off, 16);
        const float od1 = __shfl_xor(d1, off, 16);
        if (od0 < d0 || (od0 == d0 && oi0 < i0)) {
          d1 = fminf(d0, od1); d0 = od0; i0 = oi0;
        } else {
          d1 = fminf(d1, od0);
        }
      }
      if ((lane & 15) == mi * 4 + r) {
        const int n = n0 + wn * 64 + mi * 16 + (lane >> 4) * 4 + r;
        p4[(size_t)n * 2 + wk] = make_float4(d0, __int_as_float(i0), d1, 0.f);
      }
    }
  }
}

// ---------------- combine 2 partials + gather + flag ----------------
__global__ void combine_kernel(const float4* __restrict__ p4,
                               const float* __restrict__ es,
                               const float* __restrict__ usage,
                               float* __restrict__ out_q,
                               float* __restrict__ out_i,
                               int* __restrict__ list,
                               int* __restrict__ counter,
                               unsigned long long* __restrict__ rmin, int N) {
  const int wid  = threadIdx.x >> 6;
  const int lane = threadIdx.x & 63;
  const int n    = blockIdx.x * 4 + wid;

  float d0 = FLT_MAX, d1 = FLT_MAX;
  int   i0 = 0x7fffffff;
  if (lane < 2) {
    const float4 pv = p4[(size_t)n * 2 + lane];
    d0 = pv.x; i0 = __float_as_int(pv.y); d1 = pv.z;
  }
  {
    const float od0 = __shfl_xor(d0, 1, 2);
    const int   oi0 = __shfl_xor(i0, 1, 2);
    const float od1 = __shfl_xor(d1, 1, 2);
    if (od0 < d0 || (od0 == d0 && oi0 < i0)) {
      d1 = fminf(d0, od1); d0 = od0; i0 = oi0;
    } else {
      d1 = fminf(d1, od0);
    }
  }
  const int   idx = __shfl(i0, 0, 64);
  const float g0  = __shfl(d0, 0, 64);
  const float g1  = __shfl(d1, 0, 64);

  const float u = fmaxf(usage[idx], EPSILON);
  const float4 e = *(const float4*)(es + (size_t)idx * D + lane * 4);
  float4 qv;
  qv.x = e.x / u; qv.y = e.y / u; qv.z = e.z / u; qv.w = e.w / u;  // exact div
  *(float4*)(out_q + (size_t)n * D + lane * 4) = qv;
  if (lane == 0) {
    out_i[n] = (float)idx;
    if (g1 - g0 < DELTA) {
      rmin[n] = 0xFFFFFFFFFFFFFFFFull;
      const int pos = atomicAdd(counter, 1);
      list[pos] = n;
    }
  }
}

// ---------------- exact fp32 repair: 8 blocks per flagged row ----------------
__global__ void repair_kernel(const float* __restrict__ x,
                              const float* __restrict__ es,
                              const float* __restrict__ usage,
                              const float* __restrict__ esq,
                              const int* __restrict__ list,
                              const int* __restrict__ counter,
                              unsigned long long* __restrict__ rmin) {
  __shared__ float xs[256];
  const int t    = threadIdx.x;
  const int w    = t >> 6;
  const int lane = t & 63;
  const int cnt  = *counter;
  const int kseg = blockIdx.x & 7;

  for (int j = blockIdx.x >> 3; j < cnt; j += 256) {
    const int n = list[j];
    __syncthreads();
    xs[t] = x[(size_t)n * D + t];
    __syncthreads();
    const float4 xv = *(const float4*)&xs[lane * 4];

    float bd = FLT_MAX;
    int   bi = 0x7fffffff;
    const int kb0 = kseg * 256 + w * 64;
    for (int kk = 0; kk < 64; kk += 4) {
      const int kbase = kb0 + kk;
      float pd[4];
      #pragma unroll
      for (int j2 = 0; j2 < 4; ++j2) {
        const int k = kbase + j2;
        const float rs = 1.0f / fmaxf(usage[k], EPSILON);
        const float4 e = *(const float4*)(es + (size_t)k * D + lane * 4);
        float p = xv.x * (e.x * rs);
        p = fmaf(xv.y, e.y * rs, p);
        p = fmaf(xv.z, e.z * rs, p);
        pd[j2] = fmaf(xv.w, e.w * rs, p);
      }
      #pragma unroll
      for (int off = 1; off < 64; off <<= 1) {
        pd[0] += __shfl_xor(pd[0], off, 64);
        pd[1] += __shfl_xor(pd[1], off, 64);
        pd[2] += __shfl_xor(pd[2], off, 64);
        pd[3] += __shfl_xor(pd[3], off, 64);
      }
      #pragma unroll
      for (int j2 = 0; j2 < 4; ++j2) {
        const float dst = fmaf(-2.f, pd[j2], esq[kbase + j2]);
        if (dst < bd) { bd = dst; bi = kbase + j2; }
      }
    }
    if (lane == 0) {
      uint32_t ub = __float_as_uint(bd);
      ub = (ub & 0x80000000u) ? ~ub : (ub | 0x80000000u);
      const unsigned long long pk =
          ((unsigned long long)ub << 32) | (unsigned)bi;
      atomicMin(&rmin[n], pk);
    }
  }
}

// ---------------- repair pass 2: write repaired rows ----------------
__global__ void repair2_kernel(const float* __restrict__ es,
                               const float* __restrict__ usage,
                               const int* __restrict__ list,
                               const int* __restrict__ counter,
                               const unsigned long long* __restrict__ rmin,
                               float* __restrict__ out_q,
                               float* __restrict__ out_i) {
  const int t   = threadIdx.x;
  const int cnt = *counter;
  for (int j = blockIdx.x; j < cnt; j += 1024) {
    const int n   = list[j];
    const int idx = (int)(rmin[n] & 0x7fffffffu);
    const float u = fmaxf(usage[idx], EPSILON);
    out_q[(size_t)n * D + t] = es[(size_t)idx * D + t] / u;
    if (t == 0) out_i[n] = (float)idx;
  }
}

// ---------------- fallback path (R1, fp32 vector) ----------------
constexpr int TN = 128;
constexpr int DC = 32;
constexpr int KS = 2;
constexpr int RS = 196;

__global__ void esq_kernel(const float* __restrict__ es,
                           const float* __restrict__ usage,
                           float* __restrict__ esq) {
  const int lane = threadIdx.x & 63;
  const int w    = threadIdx.x >> 6;
  const int k    = blockIdx.x * 4 + w;
  const float u  = fmaxf(usage[k], EPSILON);
  const float4 e = *(const float4*)(es + (size_t)k * D + lane * 4);
  const float a = e.x / u, b = e.y / u, c = e.z / u, d = e.w / u;
  float s = a * a + b * b + c * c + d * d;
  #pragma unroll
  for (int m = 1; m < 64; m <<= 1) s += __shfl_xor(s, m, 64);
  if (lane == 0) esq[k] = s;
}

__global__ __launch_bounds__(256, 2)
void dist_kernel(const float* __restrict__ x,
                 const float* __restrict__ es,
                 const float* __restrict__ usage,
                 const float* __restrict__ esq,
                 float* __restrict__ bestd,
                 int* __restrict__ besti, int N) {
  __shared__ float smX[DC * RS];
  __shared__ float smE[DC * RS];
  const int t    = threadIdx.x;
  const int tx   = t & 15;
  const int ty   = t >> 4;
  const int n0   = blockIdx.x * TN;
  const int half = blockIdx.y;

  float best[8];
  int   bidx[8];
  #pragma unroll
  for (int i = 0; i < 8; ++i) { best[i] = FLT_MAX; bidx[i] = 0; }

  for (int kt = 0; kt < (K_TOT / KS) / 128; ++kt) {
    const int k0 = half * (K_TOT / KS) + kt * 128;
    float acc[8][8];
    #pragma unroll
    for (int i = 0; i < 8; ++i)
      #pragma unroll
      for (int j = 0; j < 8; ++j) acc[i][j] = 0.f;

    for (int dc = 0; dc < D; dc += DC) {
      __syncthreads();
      #pragma unroll
      for (int i = 0; i < 4; ++i) {
        const int f    = i * 256 + t;
        const int row  = f >> 3;
        const int c4   = f & 7;
        const int pcol = row + ((row >> 3) << 2);
        const float4 xv =
            *(const float4*)(x + (size_t)(n0 + row) * D + dc + c4 * 4);
        smX[(c4 * 4 + 0) * RS + pcol] = xv.x;
        smX[(c4 * 4 + 1) * RS + pcol] = xv.y;
        smX[(c4 * 4 + 2) * RS + pcol] = xv.z;
        smX[(c4 * 4 + 3) * RS + pcol] = xv.w;
        const int kk = k0 + row;
        const float rs = 1.0f / fmaxf(usage[kk], EPSILON);
        const float4 ev =
            *(const float4*)(es + (size_t)kk * D + dc + c4 * 4);
        smE[(c4 * 4 + 0) * RS + pcol] = ev.x * rs;
        smE[(c4 * 4 + 1) * RS + pcol] = ev.y * rs;
        smE[(c4 * 4 + 2) * RS + pcol] = ev.z * rs;
        smE[(c4 * 4 + 3) * RS + pcol] = ev.w * rs;
      }
      __syncthreads();
      #pragma unroll 4
      for (int d = 0; d < DC; ++d) {
        const float* px = &smX[d * RS + ty * 12];
        const float* pe = &smE[d * RS + tx * 12];
        const float4 xa = *(const float4*)px;
        const float4 xb = *(const float4*)(px + 4);
        const float4 ea = *(const float4*)pe;
        const float4 eb = *(const float4*)(pe + 4);
        const float xr[8] = {xa.x, xa.y, xa.z, xa.w, xb.x, xb.y, xb.z, xb.w};
        const float er[8] = {ea.x, ea.y, ea.z, ea.w, eb.x, eb.y, eb.z, eb.w};
        #pragma unroll
        for (int i = 0; i < 8; ++i)
          #pragma unroll
          for (int jj = 0; jj < 8; ++jj)
            acc[i][jj] = fmaf(xr[i], er[jj], acc[i][jj]);
      }
    }
    #pragma unroll
    for (int jj = 0; jj < 8; ++jj) {
      const int k = k0 + tx * 8 + jj;
      const float eq = esq[k];
      #pragma unroll
      for (int i = 0; i < 8; ++i) {
        const float dst = fmaf(-2.0f, acc[i][jj], eq);
        if (dst < best[i]) { best[i] = dst; bidx[i] = k; }
      }
    }
  }
  __syncthreads();
  float* rd = smX;
  int*   ri = (int*)smE;
  #pragma unroll
  for (int i = 0; i < 8; ++i) {
    const int r = ty * 8 + i;
    rd[tx * TN + r] = best[i];
    ri[tx * TN + r] = bidx[i];
  }
  __syncthreads();
  for (int off = 8; off >= 1; off >>= 1) {
    if (tx < off) {
      #pragma unroll
      for (int i = 0; i < 8; ++i) {
        const int r = ty * 8 + i;
        const float da = rd[tx * TN + r], db = rd[(tx + off) * TN + r];
        const int   ia = ri[tx * TN + r], ib = ri[(tx + off) * TN + r];
        if (db < da || (db == da && ib < ia)) {
          rd[tx * TN + r] = db;
          ri[tx * TN + r] = ib;
        }
      }
    }
    __syncthreads();
  }
  if (tx == 0) {
    #pragma unroll
    for (int i = 0; i < 8; ++i) {
      const int r = ty * 8 + i;
      bestd[(size_t)half * N + n0 + r] = rd[r];
      besti[(size_t)half * N + n0 + r] = ri[r];
    }
  }
}

__global__ void gather_kernel(const float* __restrict__ es,
                              const float* __restrict__ usage,
                              const float* __restrict__ bestd,
                              const int* __restrict__ besti,
                              float* __restrict__ out_q,
                              float* __restrict__ out_i, int N) {
  const int w    = threadIdx.x >> 6;
  const int lane = threadIdx.x & 63;
  const int n    = blockIdx.x * 4 + w;
  const float d0 = bestd[n];
  const float d1 = bestd[(size_t)N + n];
  const int   i0 = besti[n];
  const int   i1 = besti[(size_t)N + n];
  const int idx = (d1 < d0) ? i1 : i0;
  const float u = fmaxf(usage[idx], EPSILON);
  const float4 e = *(const float4*)(es + (size_t)idx * D + lane * 4);
  float4 qv;
  qv.x = e.x / u; qv.y = e.y / u; qv.z = e.z / u; qv.w = e.w / u;
  *(float4*)(out_q + (size_t)n * D + lane * 4) = qv;
  if (lane == 0) out_i[n] = (float)idx;
}

// ---------------- launch ----------------
extern "C" void kernel_launch(void* const* d_in, const int* in_sizes, int n_in,
                              void* d_out, int out_size, void* d_ws, size_t ws_size,
                              hipStream_t stream) {
  const float* x     = (const float*)d_in[0];  // [N, 256]
  const float* es    = (const float*)d_in[1];  // [2048, 256]
  const float* usage = (const float*)d_in[2];  // [2048]
  const int N = in_sizes[0] / D;               // 32768

  float* out_q = (float*)d_out;
  float* out_i = out_q + (size_t)N * D;

  const size_t EB = (size_t)K_TOT * 512 * 2;    // ec: 2 MB
  const size_t PB = (size_t)N * 2 * 16;         // p4: 1 MB
  const size_t off_p4   = EB;
  const size_t off_esq  = off_p4 + PB;
  const size_t off_list = off_esq + 8192;
  const size_t off_cnt  = off_list + (size_t)N * 4;
  const size_t off_rmin = off_cnt + 16;
  const size_t NEED     = off_rmin + (size_t)N * 8;

  char* wsb = (char*)d_ws;

  hipError_t attr_ok = hipFuncSetAttribute(
      (const void*)mm_kernel, hipFuncAttributeMaxDynamicSharedMemorySize,
      DYN_LDS);

  if (ws_size >= NEED && attr_ok == hipSuccess && (N % 128) == 0) {
    _Float16* ec   = (_Float16*)wsb;
    float4*   p4   = (float4*)(wsb + off_p4);
    float*    esq  = (float*)(wsb + off_esq);
    int*      list = (int*)(wsb + off_list);
    int*      cnt  = (int*)(wsb + off_cnt);
    unsigned long long* rmin = (unsigned long long*)(wsb + off_rmin);

    prep_kernel<<<K_TOT / 4 + 1, 256, 0, stream>>>(es, usage, ec, esq, cnt);
    mm_kernel<<<N / 128, 256, DYN_LDS, stream>>>(x, ec, esq, p4, N);
    combine_kernel<<<N / 4, 256, 0, stream>>>(p4, es, usage, out_q, out_i,
                                              list, cnt, rmin, N);
    repair_kernel<<<2048, 256, 0, stream>>>(x, es, usage, esq, list, cnt, rmin);
    repair2_kernel<<<1024, 256, 0, stream>>>(es, usage, list, cnt, rmin,
                                             out_q, out_i);
  } else {
    float* ws    = (float*)d_ws;
    float* esq   = ws;
    float* bestd = ws + K_TOT;
    int*   besti = (int*)(ws + K_TOT + (size_t)KS * N);
    esq_kernel<<<K_TOT / 4, 256, 0, stream>>>(es, usage, esq);
    dist_kernel<<<dim3(N / TN, KS), 256, 0, stream>>>(x, es, usage, esq,
                                                      bestd, besti, N);
    gather_kernel<<<N / 4, 256, 0, stream>>>(es, usage, bestd, besti,
                                             out_q, out_i, N);
  }
}